// Round 1
// baseline (188.810 us; speedup 1.0000x reference)
//
#include <hip/hip_runtime.h>
#include <hip/hip_bf16.h>

typedef __attribute__((ext_vector_type(8))) short short8;
typedef __attribute__((ext_vector_type(4))) float f32x4;

#define B_  4
#define H_  16
#define T_  4096
#define D_  128
#define BS_ 32
#define C_  128
#define BH_ (B_ * H_)

// d-permutation making each MFMA fragment's 8 bf16 contiguous (16B):
// pos = chunk32*32 + q4*8 + half16*4 + low2   where d = chunk32*32 + half16*16 + q4*4 + low2
__device__ __forceinline__ int posperm(int x) {
  return (x & ~31) | (((x >> 2) & 3) << 3) | (((x >> 4) & 1) << 2) | (x & 3);
}

__device__ __forceinline__ unsigned short f2bf(float f) {
  __hip_bfloat16 h = __float2bfloat16(f);
  return __builtin_bit_cast(unsigned short, h);
}

// ---------------- compress: mean-pool k,v -> bf16 k_cmp [C][D], vT [D][C] ----------------
// Output layout per head slab (128 rows x 128 ushorts): element at row r, position p
// stored at ushort index r*128 + (p ^ ((r&7)<<3))  (XOR swizzle kills LDS bank conflicts).
__global__ __launch_bounds__(128) void compress_kernel(
    const float* __restrict__ k, const float* __restrict__ v,
    unsigned short* __restrict__ kc, unsigned short* __restrict__ vT) {
  int blk = blockIdx.x;
  int bh  = blk >> 7;
  int c   = blk & 127;
  int d   = threadIdx.x;
  const float* kp = k + ((size_t)bh * T_ + (size_t)c * BS_) * D_ + d;
  const float* vp = v + ((size_t)bh * T_ + (size_t)c * BS_) * D_ + d;
  float ksum = 0.f, vsum = 0.f;
#pragma unroll
  for (int j = 0; j < BS_; ++j) {
    ksum += kp[j * D_];
    vsum += vp[j * D_];
  }
  ksum *= (1.0f / BS_);
  vsum *= (1.0f / BS_);
  size_t slab = (size_t)bh * (C_ * D_);
  kc[slab + (size_t)c * D_ + (posperm(d) ^ ((c & 7) << 3))] = f2bf(ksum);
  vT[slab + (size_t)d * C_ + (posperm(c) ^ ((d & 7) << 3))] = f2bf(vsum);
}

// ---------------- attention over compressed KV ----------------
// Per WG: one head, 64 q-rows (4 waves x 16 rows). LDS: k_cmp 32KB + vT 32KB.
// Swapped QK^T: S^T[c][t] = sum_d Kc[c][d] * Qs[t][d]  (A = Kc, B = Q^T)
// -> lane holds S^T[4g+r+16cm][lane&15]; P reused directly as PV A-operand.
__global__ __launch_bounds__(256) void attn_kernel(
    const float* __restrict__ q, const unsigned short* __restrict__ kc,
    const unsigned short* __restrict__ vT, float* __restrict__ out,
    float* __restrict__ score) {
  __shared__ uint4 kc_s[2048];  // [row c][16 chunks of 16B]
  __shared__ uint4 vT_s[2048];  // [row d][16 chunks]

  int blk    = blockIdx.x;
  int bh     = blk >> 6;
  int tchunk = blk & 63;
  int tid    = threadIdx.x;

  const uint4* kg = (const uint4*)(kc + (size_t)bh * (C_ * D_));
  const uint4* vg = (const uint4*)(vT + (size_t)bh * (C_ * D_));
#pragma unroll
  for (int it = 0; it < 8; ++it) {
    kc_s[it * 256 + tid] = kg[it * 256 + tid];
    vT_s[it * 256 + tid] = vg[it * 256 + tid];
  }
  __syncthreads();

  int wave = tid >> 6;
  int lane = tid & 63;
  int g    = lane >> 4;
  int lr   = lane & 15;
  int t0   = tchunk * 64 + wave * 16;  // wave's 16-row tile
  const float scale = 0.08838834764831845f;  // 1/sqrt(128)

  // Q fragments (B operand): lane holds Q[t = t0+lr][d = 4g + (i&3) + 16*(i>>2) + 32*ks]
  short8 qf[4];
  const float* qrow = q + ((size_t)bh * T_ + t0 + lr) * D_;
#pragma unroll
  for (int ks = 0; ks < 4; ++ks) {
    int d0 = 4 * g + 32 * ks;
    float4 a = *(const float4*)(qrow + d0);
    float4 b = *(const float4*)(qrow + d0 + 16);
    short8 f;
    f[0] = (short)f2bf(a.x * scale); f[1] = (short)f2bf(a.y * scale);
    f[2] = (short)f2bf(a.z * scale); f[3] = (short)f2bf(a.w * scale);
    f[4] = (short)f2bf(b.x * scale); f[5] = (short)f2bf(b.y * scale);
    f[6] = (short)f2bf(b.z * scale); f[7] = (short)f2bf(b.w * scale);
    qf[ks] = f;
  }

  // S^T accumulate: accS[cm] holds S^T[c = 4g + r + 16cm][t = t0 + lr]
  f32x4 accS[8];
#pragma unroll
  for (int cm = 0; cm < 8; ++cm) accS[cm] = f32x4{0.f, 0.f, 0.f, 0.f};
#pragma unroll
  for (int cm = 0; cm < 8; ++cm) {
    int row   = lr + 16 * cm;
    int rbase = row * 16;
    int rx    = row & 7;
#pragma unroll
    for (int ks = 0; ks < 4; ++ks) {
      uint4 kf = kc_s[rbase + ((4 * ks + g) ^ rx)];
      accS[cm] = __builtin_amdgcn_mfma_f32_16x16x32_bf16(
          __builtin_bit_cast(short8, kf), qf[ks], accS[cm], 0, 0, 0);
    }
  }

  // softmax over c for row t = t0 + lr (values spread over 4 lane-groups)
  float m = -3.0e38f;
#pragma unroll
  for (int cm = 0; cm < 8; ++cm)
#pragma unroll
    for (int r = 0; r < 4; ++r) m = fmaxf(m, accS[cm][r]);
  m = fmaxf(m, __shfl_xor(m, 16));
  m = fmaxf(m, __shfl_xor(m, 32));

  float sum = 0.f;
#pragma unroll
  for (int cm = 0; cm < 8; ++cm) {
#pragma unroll
    for (int r = 0; r < 4; ++r) {
      float p = __expf(accS[cm][r] - m);
      accS[cm][r] = p;
      sum += p;
    }
  }
  sum += __shfl_xor(sum, 16);
  sum += __shfl_xor(sum, 32);
  float inv = 1.0f / sum;

  // normalize + score output: score[b,h,t,c]
  float* srow = score + ((size_t)bh * T_ + t0 + lr) * C_;
#pragma unroll
  for (int cm = 0; cm < 8; ++cm) {
#pragma unroll
    for (int r = 0; r < 4; ++r) {
      float pn = accS[cm][r] * inv;
      accS[cm][r] = pn;
      srow[4 * g + r + 16 * cm] = pn;
    }
  }

  // P fragments for PV (A operand): i -> c = 4g + (i&3) + 16*(i>>2) + 32*ks
  short8 pf[4];
#pragma unroll
  for (int ks = 0; ks < 4; ++ks) {
    short8 f;
#pragma unroll
    for (int r = 0; r < 4; ++r) {
      f[r]     = (short)f2bf(accS[2 * ks][r]);
      f[4 + r] = (short)f2bf(accS[2 * ks + 1][r]);
    }
    pf[ks] = f;
  }

  // PV: O[t][d], B operand from vT rows (row = d), acc D-layout: O[4g+r][lr+16nt]
  float* obase = out + ((size_t)bh * T_ + t0) * D_;
#pragma unroll
  for (int nt = 0; nt < 8; ++nt) {
    f32x4 o = f32x4{0.f, 0.f, 0.f, 0.f};
    int row   = lr + 16 * nt;
    int rbase = row * 16;
    int rx    = row & 7;
#pragma unroll
    for (int ks = 0; ks < 4; ++ks) {
      uint4 vf = vT_s[rbase + ((4 * ks + g) ^ rx)];
      o = __builtin_amdgcn_mfma_f32_16x16x32_bf16(
          pf[ks], __builtin_bit_cast(short8, vf), o, 0, 0, 0);
    }
#pragma unroll
    for (int r = 0; r < 4; ++r) {
      obase[(size_t)(4 * g + r) * D_ + lr + 16 * nt] = o[r];
    }
  }
}

extern "C" void kernel_launch(void* const* d_in, const int* in_sizes, int n_in,
                              void* d_out, int out_size, void* d_ws, size_t ws_size,
                              hipStream_t stream) {
  const float* q = (const float*)d_in[0];
  const float* k = (const float*)d_in[1];
  const float* v = (const float*)d_in[2];
  float* out   = (float*)d_out;
  float* score = out + (size_t)BH_ * T_ * D_;

  unsigned short* kc = (unsigned short*)d_ws;                 // 2 MB
  unsigned short* vT = kc + (size_t)BH_ * C_ * D_;            // 2 MB

  compress_kernel<<<BH_ * C_, 128, 0, stream>>>(k, v, kc, vT);
  attn_kernel<<<BH_ * 64, 256, 0, stream>>>(q, kc, vT, out, score);
}